// Round 3
// baseline (194.323 us; speedup 1.0000x reference)
//
#include <hip/hip_runtime.h>

// SymmetricPooling: depthwise 5x5 binary-symmetric conv, VALID, stride 1.
// x: (16,128,128,32) f32 -> out: (16,124,124,288) f32, channel order c*9+f,
// f = eta*3 + phi, taps = {eta,4-eta} x {phi,4-phi} (deduped at centre).
//
// R3: no LDS, no barriers. Thread = output channel (c*9+f); block = one (b,y)
// output row, marching x. Outputs are lane-contiguous -> dense wave stores
// with no transpose. Column-sum sliding window in scalar registers. Stores are
// never drained by load waits (no fence between them). XCD-chunked block
// swizzle for input L2 reuse across adjacent y.

#define BB 16
#define HH 128
#define WW 128
#define CC 32
#define OH 124
#define OW 124
#define NF 9
#define OC (CC * NF)   // 288
#define NWG (BB * OH)  // 1984 = 8 * 248

__global__ __launch_bounds__(288)
void sympool_kernel(const float* __restrict__ x, float* __restrict__ out) {
    const int tid = threadIdx.x;       // 0..287 = output channel c*9+f
    const int c   = tid / NF;
    const int f   = tid - c * NF;
    const int eta = f / 3;
    const int phi = f - eta * 3;

    // bijective XCD-chunked swizzle (NWG % 8 == 0): consecutive y on one XCD
    const int wg  = blockIdx.x;
    const int swz = (wg & 7) * (NWG / 8) + (wg >> 3);
    const int b   = swz / OH;
    const int y   = swz - b * OH;

    const float* __restrict__ xrow = x + ((size_t)(b * HH + y)) * (WW * CC);
    const int off1 = eta * (WW * CC) + c;        // dword offset, row y+eta
    const int off2 = (4 - eta) * (WW * CC) + c;  // row y+4-eta
    const float rowsel = (eta == 2) ? 0.0f : 1.0f;  // dedup centre row

    // column weights: out = w0*(cs[x]+cs[x+4]) + w1*(cs[x+1]+cs[x+3]) + w2*cs[x+2]
    const float w0 = (phi == 0) ? 1.0f : 0.0f;
    const float w1 = (phi == 1) ? 1.0f : 0.0f;
    const float w2 = (phi == 2) ? 1.0f : 0.0f;

    // warm-up: column sums for cols 0..3
    float cs0 = fmaf(rowsel, xrow[off2 + 0 * CC], xrow[off1 + 0 * CC]);
    float cs1 = fmaf(rowsel, xrow[off2 + 1 * CC], xrow[off1 + 1 * CC]);
    float cs2 = fmaf(rowsel, xrow[off2 + 2 * CC], xrow[off1 + 2 * CC]);
    float cs3 = fmaf(rowsel, xrow[off2 + 3 * CC], xrow[off1 + 3 * CC]);

    float* __restrict__ op = out + (size_t)swz * (OW * OC) + tid;

#pragma unroll 5
    for (int s = 0; s < OW; ++s) {
        const float t1  = xrow[off1 + (s + 4) * CC];
        const float t2  = xrow[off2 + (s + 4) * CC];
        const float ncs = fmaf(rowsel, t2, t1);   // column sum at col s+4

        float o = w0 * (cs0 + ncs);
        o = fmaf(w1, cs1 + cs3, o);
        o = fmaf(w2, cs2, o);
        op[(size_t)s * OC] = o;

        cs0 = cs1; cs1 = cs2; cs2 = cs3; cs3 = ncs;  // unroll-5 renames these
    }
}

extern "C" void kernel_launch(void* const* d_in, const int* in_sizes, int n_in,
                              void* d_out, int out_size, void* d_ws, size_t ws_size,
                              hipStream_t stream) {
    const float* x = (const float*)d_in[0];
    // d_in[1] is the binary symmetric kernel; its structure is hardcoded.
    float* out = (float*)d_out;

    sympool_kernel<<<NWG, 288, 0, stream>>>(x, out);
}

// Round 5
// 71.616 us; speedup vs baseline: 2.7134x; 2.7134x over previous
//
#include <hip/hip_runtime.h>

// SymmetricPooling: depthwise 5x5 binary-symmetric conv, VALID, stride 1.
// x: (16,128,128,32) f32 -> out: (16,124,124,288) f32, channel order c*9+f,
// f = eta*3 + phi, taps = {eta,4-eta} x {phi,4-phi} (deduped at centre).
//
// R5 = R1 (best: 72.4us) + nontemporal output stores (fixed: clang native
// vector type, since __builtin_nontemporal_store rejects HIP_vector_type).
// Theory: the 283MB write-once stream thrashes the 4MiB/XCD L2
// (write-allocate), evicting the 25x-amplified input re-reads. nt stores
// bypass L2 allocation -> input stays L2-resident, write path streams.

#define BB 16
#define HH 128
#define WW 128
#define CC 32
#define OH 124
#define OW 124
#define NF 9
#define OC (CC * NF)   // 288
#define TX 4           // x positions per block
#define NXB (OW / TX)  // 31

typedef float f32x4 __attribute__((ext_vector_type(4)));

__global__ __launch_bounds__(128)
void sympool_kernel(const float* __restrict__ x, float* __restrict__ out) {
    __shared__ float tile[TX * OC];  // 1152 floats = 4.5 KB

    const int t = threadIdx.x;
    const int c = t & 31;        // channel
    const int d = t >> 5;        // 0..3, x offset within tile

    const int blk  = blockIdx.x;
    const int xb   = blk % NXB;
    const int rest = blk / NXB;
    const int y    = rest % OH;
    const int b    = rest / OH;
    const int x0   = xb * TX;
    const int xx   = x0 + d;

    // Lanes 0..31 = channels (contiguous 128B), lanes 32..63 = next x ->
    // each global_load_dword is one contiguous 256B wave transaction.
    const float* p = x + ((size_t)((b * HH + y) * WW + xx)) * CC + c;
    float v[5][5];
#pragma unroll
    for (int i = 0; i < 5; ++i) {
#pragma unroll
        for (int j = 0; j < 5; ++j) {
            v[i][j] = p[(i * WW + j) * CC];
        }
    }

    // Row sums: R[eta][j] = sum over i in {eta, 4-eta} (dedup) of v[i][j]
    float R[3][5];
#pragma unroll
    for (int j = 0; j < 5; ++j) {
        R[0][j] = v[0][j] + v[4][j];
        R[1][j] = v[1][j] + v[3][j];
        R[2][j] = v[2][j];
    }

    // Column sums -> 9 outputs, f = eta*3 + phi (LDS write: stride-9 dwords,
    // 9 coprime 32 -> bank-conflict-free)
    float* dst = &tile[d * OC + c * NF];
#pragma unroll
    for (int e = 0; e < 3; ++e) {
        dst[e * 3 + 0] = R[e][0] + R[e][4];
        dst[e * 3 + 1] = R[e][1] + R[e][3];
        dst[e * 3 + 2] = R[e][2];
    }

    __syncthreads();

    // Stream the 4x288-float tile out as aligned dwordx4, NONTEMPORAL:
    // bypass L2 allocation for the write-once output stream.
    f32x4* outv = (f32x4*)(out + ((size_t)((b * OH + y) * OW + x0)) * OC);
    const f32x4* tv = (const f32x4*)tile;
    const int nvec = TX * OC / 4;  // 288
#pragma unroll
    for (int k = 0; k < 3; ++k) {
        int idx = t + k * 128;
        if (idx < nvec) __builtin_nontemporal_store(tv[idx], &outv[idx]);
    }
}

extern "C" void kernel_launch(void* const* d_in, const int* in_sizes, int n_in,
                              void* d_out, int out_size, void* d_ws, size_t ws_size,
                              hipStream_t stream) {
    const float* x = (const float*)d_in[0];
    // d_in[1] is the binary symmetric kernel; its structure is hardcoded.
    float* out = (float*)d_out;

    const int grid = BB * OH * NXB;  // 16*124*31 = 61504
    sympool_kernel<<<grid, 128, 0, stream>>>(x, out);
}